// Round 8
// baseline (412.041 us; speedup 1.0000x reference)
//
#include <hip/hip_runtime.h>
#include <hip/hip_cooperative_groups.h>

namespace cg = cooperative_groups;

// ---------------------------------------------------------------------------
// CustomDeformableDetrMLPPredictionHead — MI355X (gfx950), round 7.
// ONE cooperative kernel, grid.sync() between phases (kills 2 device-drain
// kernel boundaries; gives the small phases full-grid occupancy):
//   phase A: pack 17 fp32 256x256 weight mats -> MFMA f16 tiles (verified)
//   phase B: proj+pq, M-tile 16 -> 532 units spread over the grid
//            (was 280 starved blocks): hs->f16 LDS -> GEMM1(+bias) ->
//            gq/gk dots -> GEMM2 -> PQt/PKt coalesced stores  (verified math)
//   phase C: fused head (verbatim round-7 logic): gates -> x1 = sparse-G
//            MFMA -> relu -> x2 MFMA -> fused relu+layer3 reduce -> out.
// ---------------------------------------------------------------------------

typedef _Float16 half8 __attribute__((ext_vector_type(8)));
typedef _Float16 half4v __attribute__((ext_vector_type(4)));
typedef float floatx4 __attribute__((ext_vector_type(4)));

#define MFMA16(a, b, c) __builtin_amdgcn_mfma_f32_16x16x32_f16((a), (b), (c), 0, 0, 0)

struct Params {
    const float *hs, *Wq, *bq, *Wk, *bk, *Wsub, *bsub, *Wobj, *bobj, *Wg, *bg,
                *W1, *b1, *W2, *b2, *W3, *b3;
    _Float16 *WT, *PQt, *PKt;
    float *g_ws, *out;
};

union MegaSM {
    struct { _Float16 Ah[32][264]; _Float16 Xb[32][264]; } B;      // 33.8 KB
    struct {
        union { _Float16 Pt[256][72]; _Float16 X[64][264]; } sm;   // 36.9 KB
        float gate[7][64];                                         // +1.8 KB
    } C;
};  // 38.7 KB -> 4 blocks/CU

__global__ __launch_bounds__(256, 4) void k_mega(Params p)
{
    __shared__ __align__(16) MegaSM S;
    int t = threadIdx.x, lane = t & 63, wv = t >> 6;
    int mr = lane & 15, hf = lane >> 4;
    int bid = blockIdx.x, nblk = gridDim.x;

    // ===== phase A: weight pack (17 * 8192 = 139264 elems-of-work) =====
    for (int e0 = bid * 256; e0 < 139264; e0 += nblk * 256) {
        int eid = e0 + t;
        int mat = eid >> 13, rem = eid & 8191;
        int tileid = rem >> 6, ln = rem & 63;
        const float* src;
        if      (mat < 6)  src = p.Wq + mat * 65536;
        else if (mat < 12) src = p.Wk + (mat - 6) * 65536;
        else if (mat == 12) src = p.Wsub;
        else if (mat == 13) src = p.Wobj;
        else if (mat == 14) src = p.W1;            // W1a: rows 0..255
        else if (mat == 15) src = p.W1 + 65536;    // W1b: rows 256..511
        else               src = p.W2;
        int nb = tileid >> 3, kb = tileid & 7;
        int n = nb * 16 + (ln & 15);
        int k = kb * 32 + (ln >> 4) * 8;
        half8 h;
        #pragma unroll
        for (int j = 0; j < 8; ++j) h[j] = (_Float16)src[(k + j) * 256 + n];
        *(half8*)(p.WT + mat * 65536 + tileid * 512 + ln * 8) = h;
    }
    cg::this_grid().sync();

    // ===== phase B: proj + pq, M-tile 16 (28 sub-problems x 19 tiles) =====
    for (int u = bid; u < 532; u += nblk) {
        __syncthreads();   // prior unit's LDS reads done
        int s = u / 19, rt = u - s * 19;
        int m0 = rt * 16;
        int qk = s & 1, rr = s >> 1;
        int l = rr % 7, b = rr / 7;
        int hs_l = (l < 6) ? l : 5;
        const float* src = p.hs + (hs_l * 2 + b) * 76800;
        int projmat = (l < 6) ? (qk * 6 + l) : (12 + qk);
        const _Float16* WprojT = p.WT + projmat * 65536;
        const _Float16* W1hT = p.WT + (14 + qk) * 65536;
        const float* bias = (l < 6) ? ((qk ? p.bk : p.bq) + l * 256)
                                    : (qk ? p.bobj : p.bsub);
        _Float16* dstP = qk ? p.PKt : p.PQt;
        const float* wvec = p.Wg + qk * 256;
        float* gdst = p.g_ws + qk * 4200 + (l * 2 + b) * 300;

        // stage 16 hs rows -> Ah f16 (16 threads/row, 16 cols each)
        {
            int row = t >> 4, qt = t & 15;
            int m = m0 + row; if (m > 299) m = 299;   // clamp; masked later
            const float* pp = src + m * 256 + qt * 16;
            #pragma unroll
            for (int i = 0; i < 4; ++i) {
                float4 v = *(const float4*)(pp + 4 * i);
                half4v h;
                h[0] = (_Float16)v.x; h[1] = (_Float16)v.y;
                h[2] = (_Float16)v.z; h[3] = (_Float16)v.w;
                *(half4v*)&S.B.Ah[row][qt * 16 + 4 * i] = h;
            }
        }
        __syncthreads();

        // GEMM1 (flipped): Q^T = Wproj^T @ hs^T
        floatx4 acc[4];
        #pragma unroll
        for (int i = 0; i < 4; ++i) acc[i] = floatx4{0.f, 0.f, 0.f, 0.f};
        for (int ks = 0; ks < 8; ++ks) {
            half8 bfr = *(const half8*)&S.B.Ah[mr][ks * 32 + hf * 8];
            #pragma unroll
            for (int mt = 0; mt < 4; ++mt) {
                half8 afr = *(const half8*)(WprojT + (((wv * 4 + mt) * 8 + ks) << 9) + lane * 8);
                acc[mt] = MFMA16(afr, bfr, acc[mt]);
            }
        }
        #pragma unroll
        for (int mt = 0; mt < 4; ++mt) {
            int n0 = wv * 64 + mt * 16 + hf * 4;
            float4 bb = *(const float4*)&bias[n0];
            float bv[4] = {bb.x, bb.y, bb.z, bb.w};
            half4v h;
            #pragma unroll
            for (int u2 = 0; u2 < 4; ++u2) h[u2] = (_Float16)(acc[mt][u2] + bv[u2]);
            *(half4v*)&S.B.Xb[mr][n0] = h;
        }
        __syncthreads();

        // gq/gk row dots
        {
            int row = t >> 4, qt = t & 15;
            half8 x0 = *(const half8*)&S.B.Xb[row][qt * 16];
            half8 x1 = *(const half8*)&S.B.Xb[row][qt * 16 + 8];
            const float* wp = wvec + qt * 16;
            float sum = 0.f;
            #pragma unroll
            for (int i = 0; i < 8; ++i) sum += (float)x0[i] * wp[i];
            #pragma unroll
            for (int i = 0; i < 8; ++i) sum += (float)x1[i] * wp[8 + i];
            sum += __shfl_xor(sum, 1);
            sum += __shfl_xor(sum, 2);
            sum += __shfl_xor(sum, 4);
            sum += __shfl_xor(sum, 8);
            int m = m0 + row;
            if (qt == 0 && m < 300) gdst[m] = sum;
        }

        // GEMM2 (flipped): P^T = W1h^T @ Q^T
        floatx4 acc2[4];
        #pragma unroll
        for (int i = 0; i < 4; ++i) acc2[i] = floatx4{0.f, 0.f, 0.f, 0.f};
        for (int ks = 0; ks < 8; ++ks) {
            half8 bfr = *(const half8*)&S.B.Xb[mr][ks * 32 + hf * 8];
            #pragma unroll
            for (int mt = 0; mt < 4; ++mt) {
                half8 afr = *(const half8*)(W1hT + (((wv * 4 + mt) * 8 + ks) << 9) + lane * 8);
                acc2[mt] = MFMA16(afr, bfr, acc2[mt]);
            }
        }
        #pragma unroll
        for (int mt = 0; mt < 4; ++mt) {
            int n0 = wv * 64 + mt * 16 + hf * 4;
            half4v h;
            #pragma unroll
            for (int u2 = 0; u2 < 4; ++u2) h[u2] = (_Float16)acc2[mt][u2];
            *(half4v*)&S.B.Ah[mr][n0] = h;   // Pst reuse
        }
        __syncthreads();

        // coalesced store of 2 it-tiles: dst[((b*38+it)*256+n)*56 + l*8 + io]
        #pragma unroll
        for (int z = 0; z < 2; ++z) {
            int task = z * 256 + t;
            int it2 = task >> 8, n = task & 255;
            int it = rt * 2 + it2;
            if (it < 38) {
                half8 h;
                #pragma unroll
                for (int io = 0; io < 8; ++io) h[io] = S.B.Ah[it2 * 8 + io][n];
                *(half8*)(dstP + ((size_t)(b * 38 + it) * 256 + n) * 56 + l * 8) = h;
            }
        }
    }
    cg::this_grid().sync();

    // ===== phase C: fused head (round-7 verified), grid-stride tiles =====
    const _Float16* W2T = p.WT + 16 * 65536;
    for (int tile = bid; tile < 2888; tile += nblk) {
        __syncthreads();   // prior tile's red reads / LDS done
        int b = tile / 1444, rem = tile - b * 1444;
        int it = rem / 38, jt = rem - it * 38;
        int i0 = it * 8, j0 = jt * 8;

        // gates: gate[l][r], r = (i_off<<3)|j_off
        float bg0 = p.bg[0];
        for (int task = t; task < 448; task += 256) {
            int l = task >> 6, row = task & 63;
            int i = i0 + (row >> 3); if (i > 299) i = 299;
            int j = j0 + (row & 7);  if (j > 299) j = 299;
            float z = p.g_ws[l * 600 + b * 300 + i]
                    + p.g_ws[4200 + l * 600 + b * 300 + j] + bg0;
            S.C.gate[l][row] = 1.0f / (1.0f + __expf(-z));
        }

        // x1-build (flipped): x1^T = [PQ;PK]^T @ G^T, two 64-K passes
        floatx4 acc1[4][4];
        #pragma unroll
        for (int i = 0; i < 4; ++i)
            #pragma unroll
            for (int j = 0; j < 4; ++j) acc1[i][j] = floatx4{0.f, 0.f, 0.f, 0.f};

        #pragma unroll
        for (int pass = 0; pass < 2; ++pass) {
            const _Float16* srcP = pass ? p.PKt : p.PQt;
            int tb = pass ? jt : it;
            const _Float16* gp = srcP + ((size_t)(b * 38 + tb) * 256 + t) * 56;
            __syncthreads();   // prev-pass Pt reads done / gates visible
            #pragma unroll
            for (int l = 0; l < 7; ++l)
                *(half8*)&S.C.sm.Pt[t][l * 8] = *(const half8*)(gp + l * 8);
            *(half8*)&S.C.sm.Pt[t][56] = half8{};   // zero pad
            __syncthreads();   // staging visible

            #pragma unroll
            for (int ktl = 0; ktl < 2; ++ktl) {
                int l = ktl * 4 + hf;            // source layer for this k-octet
                half8 bfr[4];
                #pragma unroll
                for (int nt = 0; nt < 4; ++nt) {
                    int r = nt * 16 + mr;
                    float g = (l < 7) ? S.C.gate[l][r] : 0.f;
                    _Float16 gh = (_Float16)g;
                    const _Float16 hz = (_Float16)0.f;
                    half8 f = {};
                    if (pass == 0) {             // jstar = nt*2 + (mr>>3)
                        f[nt * 2]     = (mr < 8)  ? gh : hz;
                        f[nt * 2 + 1] = (mr >= 8) ? gh : hz;
                    } else {                     // jstar = mr & 7
                        #pragma unroll
                        for (int j = 0; j < 8; ++j)
                            f[j] = (j == (mr & 7)) ? gh : hz;
                    }
                    bfr[nt] = f;
                }
                #pragma unroll
                for (int mt = 0; mt < 4; ++mt) {
                    half8 afr = *(const half8*)&S.C.sm.Pt[wv * 64 + mt * 16 + mr][ktl * 32 + hf * 8];
                    #pragma unroll
                    for (int nt = 0; nt < 4; ++nt)
                        acc1[mt][nt] = MFMA16(afr, bfr[nt], acc1[mt][nt]);
                }
            }
        }
        __syncthreads();   // Pt + gate reads done; X may overwrite union

        // epilogue 1: relu(x1 + b1) -> X[r][n], packed b64
        #pragma unroll
        for (int mt = 0; mt < 4; ++mt) {
            int n0 = wv * 64 + mt * 16 + hf * 4;
            float4 bb = *(const float4*)&p.b1[n0];
            float bv[4] = {bb.x, bb.y, bb.z, bb.w};
            #pragma unroll
            for (int nt = 0; nt < 4; ++nt) {
                int r = nt * 16 + mr;
                half4v h;
                #pragma unroll
                for (int u2 = 0; u2 < 4; ++u2) {
                    float v = acc1[mt][nt][u2] + bv[u2];
                    h[u2] = (_Float16)(v > 0.f ? v : 0.f);
                }
                *(half4v*)&S.C.sm.X[r][n0] = h;
            }
        }
        __syncthreads();

        // layer 2 (flipped): x2^T = W2^T @ x1^T
        floatx4 acc2[4][4];
        #pragma unroll
        for (int i = 0; i < 4; ++i)
            #pragma unroll
            for (int j = 0; j < 4; ++j) acc2[i][j] = floatx4{0.f, 0.f, 0.f, 0.f};
        for (int s2 = 0; s2 < 8; ++s2) {
            half8 bfr[4];
            #pragma unroll
            for (int nt = 0; nt < 4; ++nt)
                bfr[nt] = *(const half8*)&S.C.sm.X[nt * 16 + mr][s2 * 32 + hf * 8];
            #pragma unroll
            for (int mt = 0; mt < 4; ++mt) {
                half8 afr = *(const half8*)(W2T + (((wv * 4 + mt) * 8 + s2) << 9) + lane * 8);
                #pragma unroll
                for (int nt = 0; nt < 4; ++nt)
                    acc2[mt][nt] = MFMA16(afr, bfr[nt], acc2[mt][nt]);
            }
        }

        // fused epilogue 2 + layer 3
        {
            float* red = &S.C.gate[0][0];        // 256 floats; gates are dead
            float pr[4] = {0.f, 0.f, 0.f, 0.f};
            #pragma unroll
            for (int mt = 0; mt < 4; ++mt) {
                int n0 = wv * 64 + mt * 16 + hf * 4;
                float4 bb = *(const float4*)&p.b2[n0];
                float4 w3 = *(const float4*)&p.W3[n0];
                float bv[4] = {bb.x, bb.y, bb.z, bb.w};
                float wv3[4] = {w3.x, w3.y, w3.z, w3.w};
                #pragma unroll
                for (int nt = 0; nt < 4; ++nt)
                    #pragma unroll
                    for (int u2 = 0; u2 < 4; ++u2) {
                        float v = acc2[mt][nt][u2] + bv[u2];
                        v = v > 0.f ? v : 0.f;
                        pr[nt] += v * wv3[u2];
                    }
            }
            #pragma unroll
            for (int nt = 0; nt < 4; ++nt) {
                pr[nt] += __shfl_xor(pr[nt], 16);
                pr[nt] += __shfl_xor(pr[nt], 32);
            }
            if (hf == 0) {
                #pragma unroll
                for (int nt = 0; nt < 4; ++nt)
                    red[wv * 64 + nt * 16 + mr] = pr[nt];
            }
            __syncthreads();
            if (t < 64) {
                float pred = red[t] + red[64 + t] + red[128 + t] + red[192 + t] + p.b3[0];
                int i = i0 + (t >> 3), j = j0 + (t & 7);
                if (i < 300 && j < 300) {
                    int base = b * 90000 + i * 300 + j;
                    #pragma unroll
                    for (int lo = 0; lo < 6; ++lo) p.out[lo * 180000 + base] = pred;
                }
            }
        }
    }
}

// ---------------------------------------------------------------------------
extern "C" void kernel_launch(void* const* d_in, const int* in_sizes, int n_in,
                              void* d_out, int out_size, void* d_ws, size_t ws_size,
                              hipStream_t stream) {
    (void)in_sizes; (void)n_in; (void)out_size; (void)ws_size;
    char* ws = (char*)d_ws;
    float* g_ws   = (float*)ws;                  // 8,400 f
    _Float16* WT  = (_Float16*)(ws + 33600);     // 17*65536 h
    _Float16* PQt = WT + 17 * 65536;             // 1,089,536 h
    _Float16* PKt = PQt + 1089536;               // 1,089,536 h

    Params prm;
    prm.hs   = (const float*)d_in[0];
    prm.Wq   = (const float*)d_in[1];
    prm.bq   = (const float*)d_in[2];
    prm.Wk   = (const float*)d_in[3];
    prm.bk   = (const float*)d_in[4];
    prm.Wsub = (const float*)d_in[5];
    prm.bsub = (const float*)d_in[6];
    prm.Wobj = (const float*)d_in[7];
    prm.bobj = (const float*)d_in[8];
    prm.Wg   = (const float*)d_in[9];
    prm.bg   = (const float*)d_in[10];
    prm.W1   = (const float*)d_in[11];
    prm.b1   = (const float*)d_in[12];
    prm.W2   = (const float*)d_in[13];
    prm.b2   = (const float*)d_in[14];
    prm.W3   = (const float*)d_in[15];
    prm.b3   = (const float*)d_in[16];
    prm.WT = WT; prm.PQt = PQt; prm.PKt = PKt;
    prm.g_ws = g_ws; prm.out = (float*)d_out;

    int nb = 0;
    hipOccupancyMaxActiveBlocksPerMultiprocessor(&nb, k_mega, 256, 0);
    if (nb < 1) nb = 1;
    if (nb > 4) nb = 4;                 // LDS says 4/CU; co-residency cap
    dim3 grid(nb * 256), block(256);
    void* args[] = { &prm };
    hipLaunchCooperativeKernel((void*)k_mega, grid, block, args, 0, stream);
}

// Round 9
// 147.427 us; speedup vs baseline: 2.7949x; 2.7949x over previous
//
#include <hip/hip_runtime.h>

// ---------------------------------------------------------------------------
// CustomDeformableDetrMLPPredictionHead — MI355X (gfx950), round 8.
// Round-7 three-kernel structure (147.8 us best), with k_projpq re-tiled to
// M=16 (532 blocks = 2.08/CU, half the critical path) — body taken verbatim
// from the round-8 mega kernel's phase B, which passed correctness.
// NOTE (learned round 8): cooperative grid.sync() on CDNA4 forfeits per-XCD
// L2 residency (131 MB HBM fetch vs 13.5 MB) -> never again for this shape.
// ---------------------------------------------------------------------------

typedef _Float16 half8 __attribute__((ext_vector_type(8)));
typedef _Float16 half4v __attribute__((ext_vector_type(4)));
typedef float floatx4 __attribute__((ext_vector_type(4)));

#define MFMA16(a, b, c) __builtin_amdgcn_mfma_f32_16x16x32_f16((a), (b), (c), 0, 0, 0)

// ---------------- k_wprep: 17 mats -> MFMA f16 tiles (verified) ------------
__global__ __launch_bounds__(256) void k_wprep(
    const float* __restrict__ Wq, const float* __restrict__ Wk,
    const float* __restrict__ Wsub, const float* __restrict__ Wobj,
    const float* __restrict__ W1, const float* __restrict__ W2,
    _Float16* __restrict__ WT)
{
    int eid = blockIdx.x * 256 + threadIdx.x;     // 0..139263
    int mat = eid >> 13;                          // 0..16
    int rem = eid & 8191;
    int tileid = rem >> 6;
    int lane = rem & 63;
    const float* src;
    if      (mat < 6)  src = Wq + mat * 65536;
    else if (mat < 12) src = Wk + (mat - 6) * 65536;
    else if (mat == 12) src = Wsub;
    else if (mat == 13) src = Wobj;
    else if (mat == 14) src = W1;            // W1a: rows 0..255
    else if (mat == 15) src = W1 + 65536;    // W1b: rows 256..511
    else               src = W2;
    int nb = tileid >> 3, kb = tileid & 7;
    int n = nb * 16 + (lane & 15);
    int k = kb * 32 + (lane >> 4) * 8;
    half8 h;
    #pragma unroll
    for (int j = 0; j < 8; ++j) h[j] = (_Float16)src[(k + j) * 256 + n];
    *(half8*)(WT + mat * 65536 + tileid * 512 + lane * 8) = h;
}

// ---------------- k_projpq: M=16, 532 blocks (mega phase-B, verified) ------
// grid 532 = 28 sub-problems x 19 row-tiles of 16.  block 256 (4 waves).
// LDS: Ah[16][264] 8.4KB + Xb[16][264] 8.4KB = 16.9KB.
__global__ __launch_bounds__(256) void k_projpq(
    const float* __restrict__ hs, const _Float16* __restrict__ WT,
    const float* __restrict__ bq, const float* __restrict__ bk,
    const float* __restrict__ bsub, const float* __restrict__ bobj,
    const float* __restrict__ Wg,
    _Float16* __restrict__ PQt, _Float16* __restrict__ PKt,
    float* __restrict__ g_ws)
{
    __shared__ __align__(16) _Float16 Ah[16][264];   // hs f16; reused as Pst
    __shared__ __align__(16) _Float16 Xb[16][264];   // Q f16

    int t = threadIdx.x, lane = t & 63, wv = t >> 6;
    int mr = lane & 15, hf = lane >> 4;
    int u = blockIdx.x;
    int s = u / 19, rt = u - s * 19;
    int m0 = rt * 16;
    int qk = s & 1, rr = s >> 1;
    int l = rr % 7, b = rr / 7;
    int hs_l = (l < 6) ? l : 5;
    const float* src = hs + (hs_l * 2 + b) * 76800;
    int projmat = (l < 6) ? (qk * 6 + l) : (12 + qk);
    const _Float16* WprojT = WT + projmat * 65536;
    const _Float16* W1hT = WT + (14 + qk) * 65536;
    const float* bias = (l < 6) ? ((qk ? bk : bq) + l * 256) : (qk ? bobj : bsub);
    _Float16* dstP = qk ? PKt : PQt;
    const float* wvec = Wg + qk * 256;
    float* gdst = g_ws + qk * 4200 + (l * 2 + b) * 300;

    // stage 16 hs rows -> Ah f16 (16 threads/row, 16 cols each)
    {
        int row = t >> 4, qt = t & 15;
        int m = m0 + row; if (m > 299) m = 299;   // clamp; masked later
        const float* pp = src + m * 256 + qt * 16;
        #pragma unroll
        for (int i = 0; i < 4; ++i) {
            float4 v = *(const float4*)(pp + 4 * i);
            half4v h;
            h[0] = (_Float16)v.x; h[1] = (_Float16)v.y;
            h[2] = (_Float16)v.z; h[3] = (_Float16)v.w;
            *(half4v*)&Ah[row][qt * 16 + 4 * i] = h;
        }
    }
    __syncthreads();

    // GEMM1 (flipped): Q^T = Wproj^T @ hs^T
    floatx4 acc[4];
    #pragma unroll
    for (int i = 0; i < 4; ++i) acc[i] = floatx4{0.f, 0.f, 0.f, 0.f};
    for (int ks = 0; ks < 8; ++ks) {
        half8 bfr = *(const half8*)&Ah[mr][ks * 32 + hf * 8];
        #pragma unroll
        for (int mt = 0; mt < 4; ++mt) {
            half8 afr = *(const half8*)(WprojT + (((wv * 4 + mt) * 8 + ks) << 9) + lane * 8);
            acc[mt] = MFMA16(afr, bfr, acc[mt]);
        }
    }
    #pragma unroll
    for (int mt = 0; mt < 4; ++mt) {
        int n0 = wv * 64 + mt * 16 + hf * 4;
        float4 bb = *(const float4*)&bias[n0];
        float bv[4] = {bb.x, bb.y, bb.z, bb.w};
        half4v h;
        #pragma unroll
        for (int u2 = 0; u2 < 4; ++u2) h[u2] = (_Float16)(acc[mt][u2] + bv[u2]);
        *(half4v*)&Xb[mr][n0] = h;
    }
    __syncthreads();

    // gq/gk row dots
    {
        int row = t >> 4, qt = t & 15;
        half8 x0 = *(const half8*)&Xb[row][qt * 16];
        half8 x1 = *(const half8*)&Xb[row][qt * 16 + 8];
        const float* wp = wvec + qt * 16;
        float sum = 0.f;
        #pragma unroll
        for (int i = 0; i < 8; ++i) sum += (float)x0[i] * wp[i];
        #pragma unroll
        for (int i = 0; i < 8; ++i) sum += (float)x1[i] * wp[8 + i];
        sum += __shfl_xor(sum, 1);
        sum += __shfl_xor(sum, 2);
        sum += __shfl_xor(sum, 4);
        sum += __shfl_xor(sum, 8);
        int m = m0 + row;
        if (qt == 0 && m < 300) gdst[m] = sum;
    }

    // GEMM2 (flipped): P^T = W1h^T @ Q^T
    floatx4 acc2[4];
    #pragma unroll
    for (int i = 0; i < 4; ++i) acc2[i] = floatx4{0.f, 0.f, 0.f, 0.f};
    for (int ks = 0; ks < 8; ++ks) {
        half8 bfr = *(const half8*)&Xb[mr][ks * 32 + hf * 8];
        #pragma unroll
        for (int mt = 0; mt < 4; ++mt) {
            half8 afr = *(const half8*)(W1hT + (((wv * 4 + mt) * 8 + ks) << 9) + lane * 8);
            acc2[mt] = MFMA16(afr, bfr, acc2[mt]);
        }
    }
    #pragma unroll
    for (int mt = 0; mt < 4; ++mt) {
        int n0 = wv * 64 + mt * 16 + hf * 4;
        half4v h;
        #pragma unroll
        for (int u2 = 0; u2 < 4; ++u2) h[u2] = (_Float16)acc2[mt][u2];
        *(half4v*)&Ah[mr][n0] = h;   // Pst reuse
    }
    __syncthreads();

    // coalesced store of 2 it-tiles: dst[((b*38+it)*256+n)*56 + l*8 + io]
    #pragma unroll
    for (int z = 0; z < 2; ++z) {
        int task = z * 256 + t;
        int it2 = task >> 8, n = task & 255;
        int it = rt * 2 + it2;
        if (it < 38) {
            half8 h;
            #pragma unroll
            for (int io = 0; io < 8; ++io) h[io] = Ah[it2 * 8 + io][n];
            *(half8*)(dstP + ((size_t)(b * 38 + it) * 256 + n) * 56 + l * 8) = h;
        }
    }
}

// ---------------- k_fused (verbatim round 7, verified 50 us) ---------------
// grid 2*38*38 = 2888, block 256 (4 waves; waves split 256 out-cols).
// LDS: union{Pt 36.9KB, X 33.8KB} + gate 1.8KB = 38.7KB -> 4 blocks/CU.
__global__ __launch_bounds__(256, 4) void k_fused(
    const _Float16* __restrict__ PQt, const _Float16* __restrict__ PKt,
    const float* __restrict__ g_ws, const float* __restrict__ b1,
    const _Float16* __restrict__ W2T, const float* __restrict__ b2,
    const float* __restrict__ W3, const float* __restrict__ b3,
    const float* __restrict__ bg, float* __restrict__ out)
{
    union SM {
        _Float16 Pt[256][72];   // [n][k], k = l*8+io (0..55); 56..63 zero pad
        _Float16 X[64][264];    // [r][col]
    };
    __shared__ __align__(16) SM sm;
    __shared__ float gate[7][64];   // gates; reused as red[4][64] after x1

    int t = threadIdx.x, lane = t & 63, wv = t >> 6;
    int mr = lane & 15, hf = lane >> 4;
    int bid = blockIdx.x;
    int b = bid / 1444, rem = bid - b * 1444;
    int it = rem / 38, jt = rem - it * 38;
    int i0 = it * 8, j0 = jt * 8;

    // ---- gates: gate[l][r], r = (i_off<<3)|j_off (verified) ----
    float bg0 = bg[0];
    for (int task = t; task < 448; task += 256) {
        int l = task >> 6, row = task & 63;
        int i = i0 + (row >> 3); if (i > 299) i = 299;
        int j = j0 + (row & 7);  if (j > 299) j = 299;
        float z = g_ws[l * 600 + b * 300 + i] + g_ws[4200 + l * 600 + b * 300 + j] + bg0;
        gate[l][row] = 1.0f / (1.0f + __expf(-z));
    }

    // ---- x1-build (flipped): x1^T = [PQ;PK]^T @ G^T, two 64-K passes ----
    floatx4 acc1[4][4];
    #pragma unroll
    for (int i = 0; i < 4; ++i)
        #pragma unroll
        for (int j = 0; j < 4; ++j) acc1[i][j] = floatx4{0.f, 0.f, 0.f, 0.f};

    #pragma unroll
    for (int pass = 0; pass < 2; ++pass) {
        const _Float16* src = pass ? PKt : PQt;
        int tb = pass ? jt : it;
        const _Float16* gp = src + ((size_t)(b * 38 + tb) * 256 + t) * 56;
        __syncthreads();   // prev-pass Pt reads done / gates visible (pass 0)
        #pragma unroll
        for (int l = 0; l < 7; ++l)
            *(half8*)&sm.Pt[t][l * 8] = *(const half8*)(gp + l * 8);
        *(half8*)&sm.Pt[t][56] = half8{};   // zero pad
        __syncthreads();   // staging visible

        #pragma unroll
        for (int ktl = 0; ktl < 2; ++ktl) {
            int l = ktl * 4 + hf;            // source layer for this k-octet
            half8 bfr[4];
            #pragma unroll
            for (int nt = 0; nt < 4; ++nt) {
                int r = nt * 16 + mr;
                float g = (l < 7) ? gate[l][r] : 0.f;
                _Float16 gh = (_Float16)g;
                const _Float16 hz = (_Float16)0.f;
                half8 f = {};
                if (pass == 0) {             // jstar = nt*2 + (mr>>3)
                    f[nt * 2]     = (mr < 8)  ? gh : hz;
                    f[nt * 2 + 1] = (mr >= 8) ? gh : hz;
                } else {                     // jstar = mr & 7
                    #pragma unroll
                    for (int j = 0; j < 8; ++j)
                        f[j] = (j == (mr & 7)) ? gh : hz;
                }
                bfr[nt] = f;
            }
            #pragma unroll
            for (int mt = 0; mt < 4; ++mt) {
                half8 afr = *(const half8*)&sm.Pt[wv * 64 + mt * 16 + mr][ktl * 32 + hf * 8];
                #pragma unroll
                for (int nt = 0; nt < 4; ++nt)
                    acc1[mt][nt] = MFMA16(afr, bfr[nt], acc1[mt][nt]);
            }
        }
    }
    __syncthreads();   // all Pt reads + gate reads done; X may overwrite union

    // ---- epilogue 1: relu(x1 + b1) -> X[r][n], packed b64 ----
    #pragma unroll
    for (int mt = 0; mt < 4; ++mt) {
        int n0 = wv * 64 + mt * 16 + hf * 4;
        float4 bb = *(const float4*)&b1[n0];
        float bv[4] = {bb.x, bb.y, bb.z, bb.w};
        #pragma unroll
        for (int nt = 0; nt < 4; ++nt) {
            int r = nt * 16 + mr;
            half4v h;
            #pragma unroll
            for (int u = 0; u < 4; ++u) {
                float v = acc1[mt][nt][u] + bv[u];
                h[u] = (_Float16)(v > 0.f ? v : 0.f);
            }
            *(half4v*)&sm.X[r][n0] = h;
        }
    }
    __syncthreads();

    // ---- layer 2 (flipped): x2^T = W2^T @ x1^T ----
    floatx4 acc2[4][4];
    #pragma unroll
    for (int i = 0; i < 4; ++i)
        #pragma unroll
        for (int j = 0; j < 4; ++j) acc2[i][j] = floatx4{0.f, 0.f, 0.f, 0.f};
    for (int s = 0; s < 8; ++s) {
        half8 bfr[4];
        #pragma unroll
        for (int nt = 0; nt < 4; ++nt)
            bfr[nt] = *(const half8*)&sm.X[nt * 16 + mr][s * 32 + hf * 8];
        #pragma unroll
        for (int mt = 0; mt < 4; ++mt) {
            half8 afr = *(const half8*)(W2T + (((wv * 4 + mt) * 8 + s) << 9) + lane * 8);
            #pragma unroll
            for (int nt = 0; nt < 4; ++nt)
                acc2[mt][nt] = MFMA16(afr, bfr[nt], acc2[mt][nt]);
        }
    }

    // ---- fused epilogue 2 + layer 3: p[row] = relu(x2+b2) . W3 ----
    {
        float* red = &gate[0][0];            // 256 floats; gates are dead
        float p[4] = {0.f, 0.f, 0.f, 0.f};
        #pragma unroll
        for (int mt = 0; mt < 4; ++mt) {
            int n0 = wv * 64 + mt * 16 + hf * 4;
            float4 bb = *(const float4*)&b2[n0];
            float4 w3 = *(const float4*)&W3[n0];
            float bv[4] = {bb.x, bb.y, bb.z, bb.w};
            float wv3[4] = {w3.x, w3.y, w3.z, w3.w};
            #pragma unroll
            for (int nt = 0; nt < 4; ++nt)
                #pragma unroll
                for (int u = 0; u < 4; ++u) {
                    float v = acc2[mt][nt][u] + bv[u];
                    v = v > 0.f ? v : 0.f;
                    p[nt] += v * wv3[u];
                }
        }
        #pragma unroll
        for (int nt = 0; nt < 4; ++nt) {
            p[nt] += __shfl_xor(p[nt], 16);
            p[nt] += __shfl_xor(p[nt], 32);
        }
        if (hf == 0) {
            #pragma unroll
            for (int nt = 0; nt < 4; ++nt)
                red[wv * 64 + nt * 16 + mr] = p[nt];
        }
        __syncthreads();
        if (t < 64) {
            float pred = red[t] + red[64 + t] + red[128 + t] + red[192 + t] + b3[0];
            int i = i0 + (t >> 3), j = j0 + (t & 7);
            if (i < 300 && j < 300) {
                int base = b * 90000 + i * 300 + j;
                #pragma unroll
                for (int lo = 0; lo < 6; ++lo) out[lo * 180000 + base] = pred;
            }
        }
    }
}

// ---------------------------------------------------------------------------
extern "C" void kernel_launch(void* const* d_in, const int* in_sizes, int n_in,
                              void* d_out, int out_size, void* d_ws, size_t ws_size,
                              hipStream_t stream) {
    (void)in_sizes; (void)n_in; (void)out_size; (void)ws_size;
    const float* hs   = (const float*)d_in[0];
    const float* Wq   = (const float*)d_in[1];
    const float* bq   = (const float*)d_in[2];
    const float* Wk   = (const float*)d_in[3];
    const float* bk   = (const float*)d_in[4];
    const float* Wsub = (const float*)d_in[5];
    const float* bsub = (const float*)d_in[6];
    const float* Wobj = (const float*)d_in[7];
    const float* bobj = (const float*)d_in[8];
    const float* Wg   = (const float*)d_in[9];
    const float* bg   = (const float*)d_in[10];
    const float* W1   = (const float*)d_in[11];
    const float* b1   = (const float*)d_in[12];
    const float* W2   = (const float*)d_in[13];
    const float* b2   = (const float*)d_in[14];
    const float* W3   = (const float*)d_in[15];
    const float* b3   = (const float*)d_in[16];

    char* ws = (char*)d_ws;
    float* g_ws   = (float*)ws;                  // 8,400 f
    _Float16* WT  = (_Float16*)(ws + 33600);     // 17*65536 h
    _Float16* PQt = WT + 17 * 65536;             // 1,089,536 h
    _Float16* PKt = PQt + 1089536;               // 1,089,536 h

    k_wprep<<<544, 256, 0, stream>>>(Wq, Wk, Wsub, Wobj, W1, W2, WT);
    k_projpq<<<532, 256, 0, stream>>>(hs, WT, bq, bk, bsub, bobj, Wg,
                                      PQt, PKt, g_ws);
    k_fused<<<2888, 256, 0, stream>>>(PQt, PKt, g_ws, b1, WT + 16 * 65536,
                                      b2, W3, b3, bg, (float*)d_out);
}

// Round 10
// 146.640 us; speedup vs baseline: 2.8099x; 1.0054x over previous
//
#include <hip/hip_runtime.h>

// ---------------------------------------------------------------------------
// CustomDeformableDetrMLPPredictionHead — MI355X (gfx950), round 9.
// Round-8 structure, one change: P-tensor layout is now l-major
//   P[b][tb][l][n][io]  (chunk stride 2048 halves)
// so projpq's stores and k_fused's staging loads are fully coalesced
// (were 16B @ 112B stride = ~4x L2 request amplification on the post-barrier
// critical path).  W2 packing moved into k_projpq's grid tail (blocks
// 532..563; consumed only by the NEXT kernel -> no ordering hazard).
// ---------------------------------------------------------------------------

typedef _Float16 half8 __attribute__((ext_vector_type(8)));
typedef _Float16 half4v __attribute__((ext_vector_type(4)));
typedef float floatx4 __attribute__((ext_vector_type(4)));

#define MFMA16(a, b, c) __builtin_amdgcn_mfma_f32_16x16x32_f16((a), (b), (c), 0, 0, 0)

// ---------------- k_wprep: mats 0..15 -> MFMA f16 tiles (verified) ---------
__global__ __launch_bounds__(256) void k_wprep(
    const float* __restrict__ Wq, const float* __restrict__ Wk,
    const float* __restrict__ Wsub, const float* __restrict__ Wobj,
    const float* __restrict__ W1, _Float16* __restrict__ WT)
{
    int eid = blockIdx.x * 256 + threadIdx.x;     // 0..131071
    int mat = eid >> 13;                          // 0..15
    int rem = eid & 8191;
    int tileid = rem >> 6;
    int lane = rem & 63;
    const float* src;
    if      (mat < 6)  src = Wq + mat * 65536;
    else if (mat < 12) src = Wk + (mat - 6) * 65536;
    else if (mat == 12) src = Wsub;
    else if (mat == 13) src = Wobj;
    else if (mat == 14) src = W1;            // W1a: rows 0..255
    else               src = W1 + 65536;     // W1b: rows 256..511
    int nb = tileid >> 3, kb = tileid & 7;
    int n = nb * 16 + (lane & 15);
    int k = kb * 32 + (lane >> 4) * 8;
    half8 h;
    #pragma unroll
    for (int j = 0; j < 8; ++j) h[j] = (_Float16)src[(k + j) * 256 + n];
    *(half8*)(WT + mat * 65536 + tileid * 512 + lane * 8) = h;
}

// ---------------- k_projpq: M=16, 532 blocks + 32 W2-pack blocks -----------
// grid 564.  blocks < 532: 28 sub-problems x 19 row-tiles of 16 (verified).
// blocks >= 532: pack W2 -> WT[16] (consumed only by k_fused).
__global__ __launch_bounds__(256) void k_projpq(
    const float* __restrict__ hs, _Float16* __restrict__ WT,
    const float* __restrict__ bq, const float* __restrict__ bk,
    const float* __restrict__ bsub, const float* __restrict__ bobj,
    const float* __restrict__ Wg, const float* __restrict__ W2,
    _Float16* __restrict__ PQt, _Float16* __restrict__ PKt,
    float* __restrict__ g_ws)
{
    int t = threadIdx.x;
    if (blockIdx.x >= 532) {           // W2 pack tail (verified pattern)
        int eid = (blockIdx.x - 532) * 256 + t;   // 0..8191
        int tileid = eid >> 6, lane = eid & 63;
        int nb = tileid >> 3, kb = tileid & 7;
        int n = nb * 16 + (lane & 15);
        int k = kb * 32 + (lane >> 4) * 8;
        half8 h;
        #pragma unroll
        for (int j = 0; j < 8; ++j) h[j] = (_Float16)W2[(k + j) * 256 + n];
        *(half8*)(WT + 16 * 65536 + tileid * 512 + lane * 8) = h;
        return;
    }

    __shared__ __align__(16) _Float16 Ah[16][264];   // hs f16; reused as Pst
    __shared__ __align__(16) _Float16 Xb[16][264];   // Q f16

    int lane = t & 63, wv = t >> 6;
    int mr = lane & 15, hf = lane >> 4;
    int u = blockIdx.x;
    int s = u / 19, rt = u - s * 19;
    int m0 = rt * 16;
    int qk = s & 1, rr = s >> 1;
    int l = rr % 7, b = rr / 7;
    int hs_l = (l < 6) ? l : 5;
    const float* src = hs + (hs_l * 2 + b) * 76800;
    int projmat = (l < 6) ? (qk * 6 + l) : (12 + qk);
    const _Float16* WprojT = WT + projmat * 65536;
    const _Float16* W1hT = WT + (14 + qk) * 65536;
    const float* bias = (l < 6) ? ((qk ? bk : bq) + l * 256) : (qk ? bobj : bsub);
    _Float16* dstP = qk ? PKt : PQt;
    const float* wvec = Wg + qk * 256;
    float* gdst = g_ws + qk * 4200 + (l * 2 + b) * 300;

    // stage 16 hs rows -> Ah f16 (16 threads/row, 16 cols each)
    {
        int row = t >> 4, qt = t & 15;
        int m = m0 + row; if (m > 299) m = 299;   // clamp; masked later
        const float* pp = src + m * 256 + qt * 16;
        #pragma unroll
        for (int i = 0; i < 4; ++i) {
            float4 v = *(const float4*)(pp + 4 * i);
            half4v h;
            h[0] = (_Float16)v.x; h[1] = (_Float16)v.y;
            h[2] = (_Float16)v.z; h[3] = (_Float16)v.w;
            *(half4v*)&Ah[row][qt * 16 + 4 * i] = h;
        }
    }
    __syncthreads();

    // GEMM1 (flipped): Q^T = Wproj^T @ hs^T
    floatx4 acc[4];
    #pragma unroll
    for (int i = 0; i < 4; ++i) acc[i] = floatx4{0.f, 0.f, 0.f, 0.f};
    for (int ks = 0; ks < 8; ++ks) {
        half8 bfr = *(const half8*)&Ah[mr][ks * 32 + hf * 8];
        #pragma unroll
        for (int mt = 0; mt < 4; ++mt) {
            half8 afr = *(const half8*)(WprojT + (((wv * 4 + mt) * 8 + ks) << 9) + lane * 8);
            acc[mt] = MFMA16(afr, bfr, acc[mt]);
        }
    }
    #pragma unroll
    for (int mt = 0; mt < 4; ++mt) {
        int n0 = wv * 64 + mt * 16 + hf * 4;
        float4 bb = *(const float4*)&bias[n0];
        float bv[4] = {bb.x, bb.y, bb.z, bb.w};
        half4v h;
        #pragma unroll
        for (int u2 = 0; u2 < 4; ++u2) h[u2] = (_Float16)(acc[mt][u2] + bv[u2]);
        *(half4v*)&Xb[mr][n0] = h;
    }
    __syncthreads();

    // gq/gk row dots
    {
        int row = t >> 4, qt = t & 15;
        half8 x0 = *(const half8*)&Xb[row][qt * 16];
        half8 x1 = *(const half8*)&Xb[row][qt * 16 + 8];
        const float* wp = wvec + qt * 16;
        float sum = 0.f;
        #pragma unroll
        for (int i = 0; i < 8; ++i) sum += (float)x0[i] * wp[i];
        #pragma unroll
        for (int i = 0; i < 8; ++i) sum += (float)x1[i] * wp[8 + i];
        sum += __shfl_xor(sum, 1);
        sum += __shfl_xor(sum, 2);
        sum += __shfl_xor(sum, 4);
        sum += __shfl_xor(sum, 8);
        int m = m0 + row;
        if (qt == 0 && m < 300) gdst[m] = sum;
    }

    // GEMM2 (flipped): P^T = W1h^T @ Q^T
    floatx4 acc2[4];
    #pragma unroll
    for (int i = 0; i < 4; ++i) acc2[i] = floatx4{0.f, 0.f, 0.f, 0.f};
    for (int ks = 0; ks < 8; ++ks) {
        half8 bfr = *(const half8*)&Xb[mr][ks * 32 + hf * 8];
        #pragma unroll
        for (int mt = 0; mt < 4; ++mt) {
            half8 afr = *(const half8*)(W1hT + (((wv * 4 + mt) * 8 + ks) << 9) + lane * 8);
            acc2[mt] = MFMA16(afr, bfr, acc2[mt]);
        }
    }
    #pragma unroll
    for (int mt = 0; mt < 4; ++mt) {
        int n0 = wv * 64 + mt * 16 + hf * 4;
        half4v h;
        #pragma unroll
        for (int u2 = 0; u2 < 4; ++u2) h[u2] = (_Float16)acc2[mt][u2];
        *(half4v*)&Ah[mr][n0] = h;   // Pst reuse
    }
    __syncthreads();

    // coalesced store, NEW l-major layout:
    //   dst[(((b*38+it)*7 + l)*256 + n)*8 + io], wave writes 1KB contiguous
    #pragma unroll
    for (int z = 0; z < 2; ++z) {
        int it = rt * 2 + z;
        int n = t;
        half8 h;
        #pragma unroll
        for (int io = 0; io < 8; ++io) h[io] = Ah[z * 8 + io][n];
        *(half8*)(dstP + ((size_t)((b * 38 + it) * 7 + l) * 256 + n) * 8) = h;
    }
}

// ---------------- k_fused (round-7 logic; staging uses l-major layout) -----
// grid 2*38*38 = 2888, block 256 (4 waves; waves split 256 out-cols).
// LDS: union{Pt 36.9KB, X 33.8KB} + gate 1.8KB = 38.7KB -> 4 blocks/CU.
__global__ __launch_bounds__(256, 4) void k_fused(
    const _Float16* __restrict__ PQt, const _Float16* __restrict__ PKt,
    const float* __restrict__ g_ws, const float* __restrict__ b1,
    const _Float16* __restrict__ W2T, const float* __restrict__ b2,
    const float* __restrict__ W3, const float* __restrict__ b3,
    const float* __restrict__ bg, float* __restrict__ out)
{
    union SM {
        _Float16 Pt[256][72];   // [n][k], k = l*8+io (0..55); 56..63 zero pad
        _Float16 X[64][264];    // [r][col]
    };
    __shared__ __align__(16) SM sm;
    __shared__ float gate[7][64];   // gates; reused as red[4][64] after x1

    int t = threadIdx.x, lane = t & 63, wv = t >> 6;
    int mr = lane & 15, hf = lane >> 4;
    int bid = blockIdx.x;
    int b = bid / 1444, rem = bid - b * 1444;
    int it = rem / 38, jt = rem - it * 38;
    int i0 = it * 8, j0 = jt * 8;

    // ---- gates: gate[l][r], r = (i_off<<3)|j_off (verified) ----
    float bg0 = bg[0];
    for (int task = t; task < 448; task += 256) {
        int l = task >> 6, row = task & 63;
        int i = i0 + (row >> 3); if (i > 299) i = 299;
        int j = j0 + (row & 7);  if (j > 299) j = 299;
        float z = g_ws[l * 600 + b * 300 + i] + g_ws[4200 + l * 600 + b * 300 + j] + bg0;
        gate[l][row] = 1.0f / (1.0f + __expf(-z));
    }

    // ---- x1-build (flipped): x1^T = [PQ;PK]^T @ G^T, two 64-K passes ----
    floatx4 acc1[4][4];
    #pragma unroll
    for (int i = 0; i < 4; ++i)
        #pragma unroll
        for (int j = 0; j < 4; ++j) acc1[i][j] = floatx4{0.f, 0.f, 0.f, 0.f};

    #pragma unroll
    for (int pass = 0; pass < 2; ++pass) {
        const _Float16* src = pass ? PKt : PQt;
        int tb = pass ? jt : it;
        const _Float16* base = src + ((size_t)((b * 38 + tb) * 7) * 256 + t) * 8;
        __syncthreads();   // prev-pass Pt reads done / gates visible (pass 0)
        #pragma unroll
        for (int l = 0; l < 7; ++l)
            *(half8*)&sm.Pt[t][l * 8] = *(const half8*)(base + l * 2048);
        *(half8*)&sm.Pt[t][56] = half8{};   // zero pad
        __syncthreads();   // staging visible

        #pragma unroll
        for (int ktl = 0; ktl < 2; ++ktl) {
            int l = ktl * 4 + hf;            // source layer for this k-octet
            half8 bfr[4];
            #pragma unroll
            for (int nt = 0; nt < 4; ++nt) {
                int r = nt * 16 + mr;
                float g = (l < 7) ? gate[l][r] : 0.f;
                _Float16 gh = (_Float16)g;
                const _Float16 hz = (_Float16)0.f;
                half8 f = {};
                if (pass == 0) {             // jstar = nt*2 + (mr>>3)
                    f[nt * 2]     = (mr < 8)  ? gh : hz;
                    f[nt * 2 + 1] = (mr >= 8) ? gh : hz;
                } else {                     // jstar = mr & 7
                    #pragma unroll
                    for (int j = 0; j < 8; ++j)
                        f[j] = (j == (mr & 7)) ? gh : hz;
                }
                bfr[nt] = f;
            }
            #pragma unroll
            for (int mt = 0; mt < 4; ++mt) {
                half8 afr = *(const half8*)&sm.Pt[wv * 64 + mt * 16 + mr][ktl * 32 + hf * 8];
                #pragma unroll
                for (int nt = 0; nt < 4; ++nt)
                    acc1[mt][nt] = MFMA16(afr, bfr[nt], acc1[mt][nt]);
            }
        }
    }
    __syncthreads();   // all Pt reads + gate reads done; X may overwrite union

    // ---- epilogue 1: relu(x1 + b1) -> X[r][n], packed b64 ----
    #pragma unroll
    for (int mt = 0; mt < 4; ++mt) {
        int n0 = wv * 64 + mt * 16 + hf * 4;
        float4 bb = *(const float4*)&b1[n0];
        float bv[4] = {bb.x, bb.y, bb.z, bb.w};
        #pragma unroll
        for (int nt = 0; nt < 4; ++nt) {
            int r = nt * 16 + mr;
            half4v h;
            #pragma unroll
            for (int u = 0; u < 4; ++u) {
                float v = acc1[mt][nt][u] + bv[u];
                h[u] = (_Float16)(v > 0.f ? v : 0.f);
            }
            *(half4v*)&sm.X[r][n0] = h;
        }
    }
    __syncthreads();

    // ---- layer 2 (flipped): x2^T = W2^T @ x1^T ----
    floatx4 acc2[4][4];
    #pragma unroll
    for (int i = 0; i < 4; ++i)
        #pragma unroll
        for (int j = 0; j < 4; ++j) acc2[i][j] = floatx4{0.f, 0.f, 0.f, 0.f};
    for (int s = 0; s < 8; ++s) {
        half8 bfr[4];
        #pragma unroll
        for (int nt = 0; nt < 4; ++nt)
            bfr[nt] = *(const half8*)&sm.X[nt * 16 + mr][s * 32 + hf * 8];
        #pragma unroll
        for (int mt = 0; mt < 4; ++mt) {
            half8 afr = *(const half8*)(W2T + (((wv * 4 + mt) * 8 + s) << 9) + lane * 8);
            #pragma unroll
            for (int nt = 0; nt < 4; ++nt)
                acc2[mt][nt] = MFMA16(afr, bfr[nt], acc2[mt][nt]);
        }
    }

    // ---- fused epilogue 2 + layer 3: p[row] = relu(x2+b2) . W3 ----
    {
        float* red = &gate[0][0];            // 256 floats; gates are dead
        float p[4] = {0.f, 0.f, 0.f, 0.f};
        #pragma unroll
        for (int mt = 0; mt < 4; ++mt) {
            int n0 = wv * 64 + mt * 16 + hf * 4;
            float4 bb = *(const float4*)&b2[n0];
            float4 w3 = *(const float4*)&W3[n0];
            float bv[4] = {bb.x, bb.y, bb.z, bb.w};
            float wv3[4] = {w3.x, w3.y, w3.z, w3.w};
            #pragma unroll
            for (int nt = 0; nt < 4; ++nt)
                #pragma unroll
                for (int u = 0; u < 4; ++u) {
                    float v = acc2[mt][nt][u] + bv[u];
                    v = v > 0.f ? v : 0.f;
                    p[nt] += v * wv3[u];
                }
        }
        #pragma unroll
        for (int nt = 0; nt < 4; ++nt) {
            p[nt] += __shfl_xor(p[nt], 16);
            p[nt] += __shfl_xor(p[nt], 32);
        }
        if (hf == 0) {
            #pragma unroll
            for (int nt = 0; nt < 4; ++nt)
                red[wv * 64 + nt * 16 + mr] = p[nt];
        }
        __syncthreads();
        if (t < 64) {
            float pred = red[t] + red[64 + t] + red[128 + t] + red[192 + t] + b3[0];
            int i = i0 + (t >> 3), j = j0 + (t & 7);
            if (i < 300 && j < 300) {
                int base = b * 90000 + i * 300 + j;
                #pragma unroll
                for (int lo = 0; lo < 6; ++lo) out[lo * 180000 + base] = pred;
            }
        }
    }
}

// ---------------------------------------------------------------------------
extern "C" void kernel_launch(void* const* d_in, const int* in_sizes, int n_in,
                              void* d_out, int out_size, void* d_ws, size_t ws_size,
                              hipStream_t stream) {
    (void)in_sizes; (void)n_in; (void)out_size; (void)ws_size;
    const float* hs   = (const float*)d_in[0];
    const float* Wq   = (const float*)d_in[1];
    const float* bq   = (const float*)d_in[2];
    const float* Wk   = (const float*)d_in[3];
    const float* bk   = (const float*)d_in[4];
    const float* Wsub = (const float*)d_in[5];
    const float* bsub = (const float*)d_in[6];
    const float* Wobj = (const float*)d_in[7];
    const float* bobj = (const float*)d_in[8];
    const float* Wg   = (const float*)d_in[9];
    const float* bg   = (const float*)d_in[10];
    const float* W1   = (const float*)d_in[11];
    const float* b1   = (const float*)d_in[12];
    const float* W2   = (const float*)d_in[13];
    const float* b2   = (const float*)d_in[14];
    const float* W3   = (const float*)d_in[15];
    const float* b3   = (const float*)d_in[16];

    char* ws = (char*)d_ws;
    float* g_ws   = (float*)ws;                  // 8,400 f
    _Float16* WT  = (_Float16*)(ws + 33600);     // 17*65536 h
    _Float16* PQt = WT + 17 * 65536;             // 1,089,536 h (l-major layout)
    _Float16* PKt = PQt + 1089536;               // 1,089,536 h

    k_wprep<<<512, 256, 0, stream>>>(Wq, Wk, Wsub, Wobj, W1, WT);
    k_projpq<<<564, 256, 0, stream>>>(hs, WT, bq, bk, bsub, bobj, Wg, W2,
                                      PQt, PKt, g_ws);
    k_fused<<<2888, 256, 0, stream>>>(PQt, PKt, g_ws, b1, WT + 16 * 65536,
                                      b2, W3, b3, bg, (float*)d_out);
}

// Round 11
// 146.193 us; speedup vs baseline: 2.8185x; 1.0031x over previous
//
#include <hip/hip_runtime.h>

// ---------------------------------------------------------------------------
// CustomDeformableDetrMLPPredictionHead — MI355X (gfx950), round 10.
// Round-9 structure.  k_fused: PQ/PK slices register-prefetched at kernel
// start (56 VGPRs, stays at 4 waves/SIMD) -> PK staging is a no-wait reg->LDS
// write, PQ latency overlaps gate math, one barrier removed (9 -> 8).
// k_projpq: ks-loops fully unrolled so the 32 L2 fragment loads pipeline.
// Known floors: ~56 us harness per-replay overhead (round-8 datapoint);
// b128 LDS conflicts at wave64 floor; cooperative launch forbidden (L2 loss).
// ---------------------------------------------------------------------------

typedef _Float16 half8 __attribute__((ext_vector_type(8)));
typedef _Float16 half4v __attribute__((ext_vector_type(4)));
typedef float floatx4 __attribute__((ext_vector_type(4)));

#define MFMA16(a, b, c) __builtin_amdgcn_mfma_f32_16x16x32_f16((a), (b), (c), 0, 0, 0)

// ---------------- k_wprep: mats 0..15 -> MFMA f16 tiles (verified) ---------
__global__ __launch_bounds__(256) void k_wprep(
    const float* __restrict__ Wq, const float* __restrict__ Wk,
    const float* __restrict__ Wsub, const float* __restrict__ Wobj,
    const float* __restrict__ W1, _Float16* __restrict__ WT)
{
    int eid = blockIdx.x * 256 + threadIdx.x;     // 0..131071
    int mat = eid >> 13;                          // 0..15
    int rem = eid & 8191;
    int tileid = rem >> 6;
    int lane = rem & 63;
    const float* src;
    if      (mat < 6)  src = Wq + mat * 65536;
    else if (mat < 12) src = Wk + (mat - 6) * 65536;
    else if (mat == 12) src = Wsub;
    else if (mat == 13) src = Wobj;
    else if (mat == 14) src = W1;            // W1a: rows 0..255
    else               src = W1 + 65536;     // W1b: rows 256..511
    int nb = tileid >> 3, kb = tileid & 7;
    int n = nb * 16 + (lane & 15);
    int k = kb * 32 + (lane >> 4) * 8;
    half8 h;
    #pragma unroll
    for (int j = 0; j < 8; ++j) h[j] = (_Float16)src[(k + j) * 256 + n];
    *(half8*)(WT + mat * 65536 + tileid * 512 + lane * 8) = h;
}

// ---------------- k_projpq: M=16, 532 blocks + 32 W2-pack blocks -----------
__global__ __launch_bounds__(256) void k_projpq(
    const float* __restrict__ hs, _Float16* __restrict__ WT,
    const float* __restrict__ bq, const float* __restrict__ bk,
    const float* __restrict__ bsub, const float* __restrict__ bobj,
    const float* __restrict__ Wg, const float* __restrict__ W2,
    _Float16* __restrict__ PQt, _Float16* __restrict__ PKt,
    float* __restrict__ g_ws)
{
    int t = threadIdx.x;
    if (blockIdx.x >= 532) {           // W2 pack tail (verified pattern)
        int eid = (blockIdx.x - 532) * 256 + t;   // 0..8191
        int tileid = eid >> 6, lane = eid & 63;
        int nb = tileid >> 3, kb = tileid & 7;
        int n = nb * 16 + (lane & 15);
        int k = kb * 32 + (lane >> 4) * 8;
        half8 h;
        #pragma unroll
        for (int j = 0; j < 8; ++j) h[j] = (_Float16)W2[(k + j) * 256 + n];
        *(half8*)(WT + 16 * 65536 + tileid * 512 + lane * 8) = h;
        return;
    }

    __shared__ __align__(16) _Float16 Ah[16][264];   // hs f16; reused as Pst
    __shared__ __align__(16) _Float16 Xb[16][264];   // Q f16

    int lane = t & 63, wv = t >> 6;
    int mr = lane & 15, hf = lane >> 4;
    int u = blockIdx.x;
    int s = u / 19, rt = u - s * 19;
    int m0 = rt * 16;
    int qk = s & 1, rr = s >> 1;
    int l = rr % 7, b = rr / 7;
    int hs_l = (l < 6) ? l : 5;
    const float* src = hs + (hs_l * 2 + b) * 76800;
    int projmat = (l < 6) ? (qk * 6 + l) : (12 + qk);
    const _Float16* WprojT = WT + projmat * 65536;
    const _Float16* W1hT = WT + (14 + qk) * 65536;
    const float* bias = (l < 6) ? ((qk ? bk : bq) + l * 256) : (qk ? bobj : bsub);
    _Float16* dstP = qk ? PKt : PQt;
    const float* wvec = Wg + qk * 256;
    float* gdst = g_ws + qk * 4200 + (l * 2 + b) * 300;

    // stage 16 hs rows -> Ah f16 (16 threads/row, 16 cols each)
    {
        int row = t >> 4, qt = t & 15;
        int m = m0 + row; if (m > 299) m = 299;   // clamp; masked later
        const float* pp = src + m * 256 + qt * 16;
        #pragma unroll
        for (int i = 0; i < 4; ++i) {
            float4 v = *(const float4*)(pp + 4 * i);
            half4v h;
            h[0] = (_Float16)v.x; h[1] = (_Float16)v.y;
            h[2] = (_Float16)v.z; h[3] = (_Float16)v.w;
            *(half4v*)&Ah[row][qt * 16 + 4 * i] = h;
        }
    }
    __syncthreads();

    // GEMM1 (flipped): Q^T = Wproj^T @ hs^T   (unrolled: 32 L2 loads pipeline)
    floatx4 acc[4];
    #pragma unroll
    for (int i = 0; i < 4; ++i) acc[i] = floatx4{0.f, 0.f, 0.f, 0.f};
    #pragma unroll
    for (int ks = 0; ks < 8; ++ks) {
        half8 bfr = *(const half8*)&Ah[mr][ks * 32 + hf * 8];
        #pragma unroll
        for (int mt = 0; mt < 4; ++mt) {
            half8 afr = *(const half8*)(WprojT + (((wv * 4 + mt) * 8 + ks) << 9) + lane * 8);
            acc[mt] = MFMA16(afr, bfr, acc[mt]);
        }
    }
    #pragma unroll
    for (int mt = 0; mt < 4; ++mt) {
        int n0 = wv * 64 + mt * 16 + hf * 4;
        float4 bb = *(const float4*)&bias[n0];
        float bv[4] = {bb.x, bb.y, bb.z, bb.w};
        half4v h;
        #pragma unroll
        for (int u2 = 0; u2 < 4; ++u2) h[u2] = (_Float16)(acc[mt][u2] + bv[u2]);
        *(half4v*)&Xb[mr][n0] = h;
    }
    __syncthreads();

    // gq/gk row dots
    {
        int row = t >> 4, qt = t & 15;
        half8 x0 = *(const half8*)&Xb[row][qt * 16];
        half8 x1 = *(const half8*)&Xb[row][qt * 16 + 8];
        const float* wp = wvec + qt * 16;
        float sum = 0.f;
        #pragma unroll
        for (int i = 0; i < 8; ++i) sum += (float)x0[i] * wp[i];
        #pragma unroll
        for (int i = 0; i < 8; ++i) sum += (float)x1[i] * wp[8 + i];
        sum += __shfl_xor(sum, 1);
        sum += __shfl_xor(sum, 2);
        sum += __shfl_xor(sum, 4);
        sum += __shfl_xor(sum, 8);
        int m = m0 + row;
        if (qt == 0 && m < 300) gdst[m] = sum;
    }

    // GEMM2 (flipped): P^T = W1h^T @ Q^T   (unrolled)
    floatx4 acc2[4];
    #pragma unroll
    for (int i = 0; i < 4; ++i) acc2[i] = floatx4{0.f, 0.f, 0.f, 0.f};
    #pragma unroll
    for (int ks = 0; ks < 8; ++ks) {
        half8 bfr = *(const half8*)&Xb[mr][ks * 32 + hf * 8];
        #pragma unroll
        for (int mt = 0; mt < 4; ++mt) {
            half8 afr = *(const half8*)(W1hT + (((wv * 4 + mt) * 8 + ks) << 9) + lane * 8);
            acc2[mt] = MFMA16(afr, bfr, acc2[mt]);
        }
    }
    #pragma unroll
    for (int mt = 0; mt < 4; ++mt) {
        int n0 = wv * 64 + mt * 16 + hf * 4;
        half4v h;
        #pragma unroll
        for (int u2 = 0; u2 < 4; ++u2) h[u2] = (_Float16)acc2[mt][u2];
        *(half4v*)&Ah[mr][n0] = h;   // Pst reuse
    }
    __syncthreads();

    // coalesced store, l-major layout:
    //   dst[(((b*38+it)*7 + l)*256 + n)*8 + io], wave writes 1KB contiguous
    #pragma unroll
    for (int z = 0; z < 2; ++z) {
        int it = rt * 2 + z;
        int n = t;
        half8 h;
        #pragma unroll
        for (int io = 0; io < 8; ++io) h[io] = Ah[z * 8 + io][n];
        *(half8*)(dstP + ((size_t)((b * 38 + it) * 7 + l) * 256 + n) * 8) = h;
    }
}

// ---------------- k_fused: register-prefetched staging ---------------------
// grid 2*38*38 = 2888, block 256 (4 waves; waves split 256 out-cols).
// LDS: union{Pt 36.9KB, X 33.8KB} + gate 1.8KB = 38.7KB -> 4 blocks/CU.
// PQ/PK prefetched into 56 VGPRs at start: PK staging = reg->LDS, no vmcnt
// stall between the pass0/pass1 barriers; 8 barriers/block (was 9).
__global__ __launch_bounds__(256, 4) void k_fused(
    const _Float16* __restrict__ PQt, const _Float16* __restrict__ PKt,
    const float* __restrict__ g_ws, const float* __restrict__ b1,
    const _Float16* __restrict__ W2T, const float* __restrict__ b2,
    const float* __restrict__ W3, const float* __restrict__ b3,
    const float* __restrict__ bg, float* __restrict__ out)
{
    union SM {
        _Float16 Pt[256][72];   // [n][k], k = l*8+io (0..55); 56..63 zero pad
        _Float16 X[64][264];    // [r][col]
    };
    __shared__ __align__(16) SM sm;
    __shared__ float gate[7][64];   // gates; reused as red[4][64] at the end

    int t = threadIdx.x, lane = t & 63, wv = t >> 6;
    int mr = lane & 15, hf = lane >> 4;
    int bid = blockIdx.x;
    int b = bid / 1444, rem = bid - b * 1444;
    int it = rem / 38, jt = rem - it * 38;
    int i0 = it * 8, j0 = jt * 8;

    // ---- prefetch both P slices into registers (L2 latency overlaps gates)
    const _Float16* baseQ = PQt + ((size_t)((b * 38 + it) * 7) * 256 + t) * 8;
    const _Float16* baseK = PKt + ((size_t)((b * 38 + jt) * 7) * 256 + t) * 8;
    half8 pq[7], pk[7];
    #pragma unroll
    for (int l = 0; l < 7; ++l) pq[l] = *(const half8*)(baseQ + l * 2048);
    #pragma unroll
    for (int l = 0; l < 7; ++l) pk[l] = *(const half8*)(baseK + l * 2048);

    // ---- gates: gate[l][r], r = (i_off<<3)|j_off (verified) ----
    float bg0 = bg[0];
    for (int task = t; task < 448; task += 256) {
        int l = task >> 6, row = task & 63;
        int i = i0 + (row >> 3); if (i > 299) i = 299;
        int j = j0 + (row & 7);  if (j > 299) j = 299;
        float z = g_ws[l * 600 + b * 300 + i] + g_ws[4200 + l * 600 + b * 300 + j] + bg0;
        gate[l][row] = 1.0f / (1.0f + __expf(-z));
    }

    // ---- stage PQ -> Pt (pq regs already waited by compiler) ----
    #pragma unroll
    for (int l = 0; l < 7; ++l)
        *(half8*)&sm.Pt[t][l * 8] = pq[l];
    *(half8*)&sm.Pt[t][56] = half8{};   // zero pad (persists for pass 1)
    __syncthreads();   // Pt(PQ) + gates visible

    floatx4 acc1[4][4];
    #pragma unroll
    for (int i = 0; i < 4; ++i)
        #pragma unroll
        for (int j = 0; j < 4; ++j) acc1[i][j] = floatx4{0.f, 0.f, 0.f, 0.f};

    // ---- pass 0 (out_q): B one-hot jstar = nt*2 + (mr>>3) ----
    #pragma unroll
    for (int ktl = 0; ktl < 2; ++ktl) {
        int l = ktl * 4 + hf;
        half8 bfr[4];
        #pragma unroll
        for (int nt = 0; nt < 4; ++nt) {
            int r = nt * 16 + mr;
            float g = (l < 7) ? gate[l][r] : 0.f;
            _Float16 gh = (_Float16)g;
            const _Float16 hz = (_Float16)0.f;
            half8 f = {};
            f[nt * 2]     = (mr < 8)  ? gh : hz;
            f[nt * 2 + 1] = (mr >= 8) ? gh : hz;
            bfr[nt] = f;
        }
        #pragma unroll
        for (int mt = 0; mt < 4; ++mt) {
            half8 afr = *(const half8*)&sm.Pt[wv * 64 + mt * 16 + mr][ktl * 32 + hf * 8];
            #pragma unroll
            for (int nt = 0; nt < 4; ++nt)
                acc1[mt][nt] = MFMA16(afr, bfr[nt], acc1[mt][nt]);
        }
    }
    __syncthreads();   // pass-0 Pt reads done

    // ---- stage PK -> Pt from registers (no global wait) ----
    #pragma unroll
    for (int l = 0; l < 7; ++l)
        *(half8*)&sm.Pt[t][l * 8] = pk[l];
    __syncthreads();   // staging visible

    // ---- pass 1 (out_k): B one-hot jstar = mr & 7 ----
    #pragma unroll
    for (int ktl = 0; ktl < 2; ++ktl) {
        int l = ktl * 4 + hf;
        half8 bfr[4];
        #pragma unroll
        for (int nt = 0; nt < 4; ++nt) {
            int r = nt * 16 + mr;
            float g = (l < 7) ? gate[l][r] : 0.f;
            _Float16 gh = (_Float16)g;
            const _Float16 hz = (_Float16)0.f;
            half8 f = {};
            #pragma unroll
            for (int j = 0; j < 8; ++j)
                f[j] = (j == (mr & 7)) ? gh : hz;
            bfr[nt] = f;
        }
        #pragma unroll
        for (int mt = 0; mt < 4; ++mt) {
            half8 afr = *(const half8*)&sm.Pt[wv * 64 + mt * 16 + mr][ktl * 32 + hf * 8];
            #pragma unroll
            for (int nt = 0; nt < 4; ++nt)
                acc1[mt][nt] = MFMA16(afr, bfr[nt], acc1[mt][nt]);
        }
    }
    __syncthreads();   // Pt + gate reads done; X may overwrite union

    // ---- epilogue 1: relu(x1 + b1) -> X[r][n], packed b64 ----
    #pragma unroll
    for (int mt = 0; mt < 4; ++mt) {
        int n0 = wv * 64 + mt * 16 + hf * 4;
        float4 bb = *(const float4*)&b1[n0];
        float bv[4] = {bb.x, bb.y, bb.z, bb.w};
        #pragma unroll
        for (int nt = 0; nt < 4; ++nt) {
            int r = nt * 16 + mr;
            half4v h;
            #pragma unroll
            for (int u = 0; u < 4; ++u) {
                float v = acc1[mt][nt][u] + bv[u];
                h[u] = (_Float16)(v > 0.f ? v : 0.f);
            }
            *(half4v*)&sm.X[r][n0] = h;
        }
    }
    __syncthreads();

    // ---- layer 2 (flipped): x2^T = W2^T @ x1^T ----
    floatx4 acc2[4][4];
    #pragma unroll
    for (int i = 0; i < 4; ++i)
        #pragma unroll
        for (int j = 0; j < 4; ++j) acc2[i][j] = floatx4{0.f, 0.f, 0.f, 0.f};
    for (int s = 0; s < 8; ++s) {
        half8 bfr[4];
        #pragma unroll
        for (int nt = 0; nt < 4; ++nt)
            bfr[nt] = *(const half8*)&sm.X[nt * 16 + mr][s * 32 + hf * 8];
        #pragma unroll
        for (int mt = 0; mt < 4; ++mt) {
            half8 afr = *(const half8*)(W2T + (((wv * 4 + mt) * 8 + s) << 9) + lane * 8);
            #pragma unroll
            for (int nt = 0; nt < 4; ++nt)
                acc2[mt][nt] = MFMA16(afr, bfr[nt], acc2[mt][nt]);
        }
    }

    // ---- fused epilogue 2 + layer 3: p[row] = relu(x2+b2) . W3 ----
    {
        float* red = &gate[0][0];            // 256 floats; gates are dead
        float p[4] = {0.f, 0.f, 0.f, 0.f};
        #pragma unroll
        for (int mt = 0; mt < 4; ++mt) {
            int n0 = wv * 64 + mt * 16 + hf * 4;
            float4 bb = *(const float4*)&b2[n0];
            float4 w3 = *(const float4*)&W3[n0];
            float bv[4] = {bb.x, bb.y, bb.z, bb.w};
            float wv3[4] = {w3.x, w3.y, w3.z, w3.w};
            #pragma unroll
            for (int nt = 0; nt < 4; ++nt)
                #pragma unroll
                for (int u = 0; u < 4; ++u) {
                    float v = acc2[mt][nt][u] + bv[u];
                    v = v > 0.f ? v : 0.f;
                    p[nt] += v * wv3[u];
                }
        }
        #pragma unroll
        for (int nt = 0; nt < 4; ++nt) {
            p[nt] += __shfl_xor(p[nt], 16);
            p[nt] += __shfl_xor(p[nt], 32);
        }
        if (hf == 0) {
            #pragma unroll
            for (int nt = 0; nt < 4; ++nt)
                red[wv * 64 + nt * 16 + mr] = p[nt];
        }
        __syncthreads();
        if (t < 64) {
            float pred = red[t] + red[64 + t] + red[128 + t] + red[192 + t] + b3[0];
            int i = i0 + (t >> 3), j = j0 + (t & 7);
            if (i < 300 && j < 300) {
                int base = b * 90000 + i * 300 + j;
                #pragma unroll
                for (int lo = 0; lo < 6; ++lo) out[lo * 180000 + base] = pred;
            }
        }
    }
}

// ---------------------------------------------------------------------------
extern "C" void kernel_launch(void* const* d_in, const int* in_sizes, int n_in,
                              void* d_out, int out_size, void* d_ws, size_t ws_size,
                              hipStream_t stream) {
    (void)in_sizes; (void)n_in; (void)out_size; (void)ws_size;
    const float* hs   = (const float*)d_in[0];
    const float* Wq   = (const float*)d_in[1];
    const float* bq   = (const float*)d_in[2];
    const float* Wk   = (const float*)d_in[3];
    const float* bk   = (const float*)d_in[4];
    const float* Wsub = (const float*)d_in[5];
    const float* bsub = (const float*)d_in[6];
    const float* Wobj = (const float*)d_in[7];
    const float* bobj = (const float*)d_in[8];
    const float* Wg   = (const float*)d_in[9];
    const float* bg   = (const float*)d_in[10];
    const float* W1   = (const float*)d_in[11];
    const float* b1   = (const float*)d_in[12];
    const float* W2   = (const float*)d_in[13];
    const float* b2   = (const float*)d_in[14];
    const float* W3   = (const float*)d_in[15];
    const float* b3   = (const float*)d_in[16];

    char* ws = (char*)d_ws;
    float* g_ws   = (float*)ws;                  // 8,400 f
    _Float16* WT  = (_Float16*)(ws + 33600);     // 17*65536 h
    _Float16* PQt = WT + 17 * 65536;             // 1,089,536 h (l-major layout)
    _Float16* PKt = PQt + 1089536;               // 1,089,536 h

    k_wprep<<<512, 256, 0, stream>>>(Wq, Wk, Wsub, Wobj, W1, WT);
    k_projpq<<<564, 256, 0, stream>>>(hs, WT, bq, bk, bsub, bobj, Wg, W2,
                                      PQt, PKt, g_ws);
    k_fused<<<2888, 256, 0, stream>>>(PQt, PKt, g_ws, b1, WT + 16 * 65536,
                                      b2, W3, b3, bg, (float*)d_out);
}